// Round 8
// baseline (353.085 us; speedup 1.0000x reference)
//
#include <hip/hip_runtime.h>
#include <hip/hip_bf16.h>

#define ROWS 1025   // B*N + 1
#define DD   128    // D
#define C3   384    // 3*D
#define BB   8
#define NN   128

#define NL2E  (-1.4426950408889634f)   // -log2(e)

__device__ __forceinline__ unsigned short f2bf(float f) {
    unsigned int i = __float_as_uint(f);            // finite data only
    return (unsigned short)((i + 0x7FFFu + ((i >> 16) & 1u)) >> 16);
}

// Pre-scaled packed gate tables, bf16x4 per (row, d):
//   GiP[row][d] = {-L*ir, -L*iz, -2L*in, (unused)}
//   GhP[row][d] = {-L*hr, -L*hz, -2L*hn, h}
// Block = 4 hidden rows; 256 threads. Combined weight rows cc2 in [0,768):
// cc2 < 384 -> Wi row cc2 ; else Wh row cc2-384.
// Thread t owns combined col c*256+t in chunk c (c=0..2). Weights staged
// through LDS in 12 sub-tiles of [256 rows x 32 k] with coalesced global
// reads (128B runs) and pad-9 float4 LDS rows (conflict-free both sides),
// register double-buffered so next tile's loads overlap current FMAs.
__global__ __launch_bounds__(256) void gtab_kernel(
    const float* __restrict__ h,
    const float* __restrict__ Wi, const float* __restrict__ Wh,
    const float* __restrict__ bi, const float* __restrict__ bh,
    unsigned short* __restrict__ GiP, unsigned short* __restrict__ GhP) {
    __shared__ float  hs[4][DD];        // 2 KB
    __shared__ float4 wch[256][9];      // 36 KB, [m][k4] pad-9
    const int t  = threadIdx.x;
    const int r0 = blockIdx.x * 4;
    for (int idx = t; idx < 4 * DD; idx += 256) {
        const int r = idx >> 7, k = idx & (DD - 1);
        hs[r][k] = (r0 + r < ROWS) ? h[(size_t)(r0 + r) * DD + k] : 0.0f;
    }
    __syncthreads();

    // h-value pass (GhP slot 3)
    if (t < DD) {
#pragma unroll
        for (int r = 0; r < 4; ++r)
            if (r0 + r < ROWS) GhP[(size_t)(r0 + r) * 512 + t * 4 + 3] = f2bf(hs[r][t]);
    }

    const int mloc = t >> 3;            // staging: local row within 32-row group
    const int kloc = t & 7;             // staging: float4 index within 32-k slice
    float4 stg[8];

    auto LOAD = [&](int c, int ks) {
#pragma unroll
        for (int i = 0; i < 8; ++i) {
            const int m   = i * 32 + mloc;
            const int cc2 = c * 256 + m;
            const float* __restrict__ src =
                (cc2 < C3) ? (Wi + (size_t)cc2 * DD) : (Wh + (size_t)(cc2 - C3) * DD);
            stg[i] = *reinterpret_cast<const float4*>(src + ks * 32 + kloc * 4);
        }
    };
    LOAD(0, 0);

    for (int c = 0; c < 3; ++c) {
        const int  cc2  = c * 256 + t;
        const bool isI  = cc2 < C3;
        const int  cc   = isI ? cc2 : cc2 - C3;
        const int  gate = cc >> 7, d = cc & (DD - 1);
        const float bv  = (isI ? bi : bh)[cc];
        float acc[4] = {bv, bv, bv, bv};
#pragma unroll
        for (int ks = 0; ks < 4; ++ks) {
            __syncthreads();
#pragma unroll
            for (int i = 0; i < 8; ++i) wch[i * 32 + mloc][kloc] = stg[i];
            __syncthreads();
            const int s = c * 4 + ks + 1;
            if (s < 12) LOAD(s >> 2, s & 3);     // prefetch next tile
#pragma unroll
            for (int k4 = 0; k4 < 8; ++k4) {
                const float4 w = wch[t][k4];
                const int k = ks * 32 + k4 * 4;
#pragma unroll
                for (int r = 0; r < 4; ++r) {
                    acc[r] += hs[r][k] * w.x + hs[r][k + 1] * w.y
                            + hs[r][k + 2] * w.z + hs[r][k + 3] * w.w;
                }
            }
        }
        const float scale = (gate == 2) ? 2.0f * NL2E : NL2E;
        unsigned short* __restrict__ G = isI ? GiP : GhP;
#pragma unroll
        for (int r = 0; r < 4; ++r)
            if (r0 + r < ROWS) G[(size_t)(r0 + r) * 512 + d * 4 + gate] = f2bf(acc[r] * scale);
    }
}

// One block per (b,j); 512 threads = (ic 0..3) x (d 0..127); quarter ic sums 32 i's.
// XC=1: x=child, h=parent (bwd). XC=0: x=parent, h=child (fwd).   [R6 verbatim]
template<int XC, int WRITE_OUT>
__global__ __launch_bounds__(512, 4) void phase_kernel(
    const float* __restrict__ hin,
    const int* __restrict__ parent, const int* __restrict__ child,
    const unsigned short* __restrict__ GiP, const unsigned short* __restrict__ GhP,
    float* __restrict__ hout,
    const int* __restrict__ tgt, float* __restrict__ out) {
    const int bj = blockIdx.x;          // 0..1023
    const int t  = threadIdx.x;
    const int b  = bj >> 7, j = bj & (NN - 1);
    const size_t base = (size_t)b * NN * NN + j;          // + i*NN

    __shared__ int   pcs[2 * NN];       // interleaved {p,c} pairs
    __shared__ float sacc[4][DD];
    if (t < NN)            pcs[2 * t]            = parent[base + (size_t)t * NN];
    else if (t < 2 * NN)   pcs[2 * (t - NN) + 1] = child [base + (size_t)(t - NN) * NN];
    __syncthreads();

    const int ic = t >> 7, d = t & (DD - 1);
    float acc = 0.0f;
#pragma unroll 4
    for (int k = 0; k < 32; ++k) {
        const int  i  = ic * 32 + k;
        const int2 pc = *reinterpret_cast<const int2*>(&pcs[2 * i]);
        const int  xi = XC ? pc.y : pc.x;
        const int  hi = XC ? pc.x : pc.y;
        const ushort4 vx = *reinterpret_cast<const ushort4*>(GiP + (size_t)xi * 512 + d * 4);
        const ushort4 vh = *reinterpret_cast<const ushort4*>(GhP + (size_t)hi * 512 + d * 4);
        const float irs = __uint_as_float(((unsigned int)vx.x) << 16);
        const float izs = __uint_as_float(((unsigned int)vx.y) << 16);
        const float ins = __uint_as_float(((unsigned int)vx.z) << 16);
        const float hrs = __uint_as_float(((unsigned int)vh.x) << 16);
        const float hzs = __uint_as_float(((unsigned int)vh.y) << 16);
        const float hns = __uint_as_float(((unsigned int)vh.z) << 16);
        const float hv  = __uint_as_float(((unsigned int)vh.w) << 16);
        const float r = __builtin_amdgcn_rcpf(1.0f + __builtin_amdgcn_exp2f(irs + hrs));
        const float z = __builtin_amdgcn_rcpf(1.0f + __builtin_amdgcn_exp2f(izs + hzs));
        const float q = __builtin_amdgcn_rcpf(1.0f + __builtin_amdgcn_exp2f(ins + r * hns));
        const float n = 2.0f * q - 1.0f;
        acc += n + z * (hv - n);
    }
    sacc[ic][d] = acc;
    __syncthreads();

    if (ic == 0) {
        const float v   = sacc[0][d] + sacc[1][d] + sacc[2][d] + sacc[3][d];
        const int   row = 1 + bj;
        const float res = hin[(size_t)row * DD + d] + v;
        if (WRITE_OUT) {
#pragma unroll
            for (int bb = 0; bb < BB; ++bb)
                if (tgt[bb] == row) out[bb * DD + d] = res;
        } else {
            hout[(size_t)row * DD + d] = res;
        }
    } else if (ic == 1 && bj == 0 && !WRITE_OUT) {
        hout[d] = hin[d];                 // row 0 unchanged (tgt >= 1 always)
    }
}

extern "C" void kernel_launch(void* const* d_in, const int* in_sizes, int n_in,
                              void* d_out, int out_size, void* d_ws, size_t ws_size,
                              hipStream_t stream) {
    const float* hidden = (const float*)d_in[0];
    const int*   parent = (const int*)d_in[1];
    const int*   child  = (const int*)d_in[2];
    const int*   tgt    = (const int*)d_in[3];
    const float* Wif    = (const float*)d_in[4];
    const float* Whf    = (const float*)d_in[5];
    const float* bif    = (const float*)d_in[6];
    const float* bhf    = (const float*)d_in[7];
    const float* Wib    = (const float*)d_in[8];
    const float* Whb    = (const float*)d_in[9];
    const float* bib    = (const float*)d_in[10];
    const float* bhb    = (const float*)d_in[11];

    char* ws = (char*)d_ws;
    unsigned short* GiP = (unsigned short*)(ws);                  // 1025*512 bf16
    unsigned short* GhP = (unsigned short*)(ws + 1049600);        // 1025*512 bf16
    float*          h1  = (float*)(ws + 2099200);                 // 1025*128 f32
    float*          out = (float*)d_out;

    // Phase 1: bwd weights, x = child, h = parent
    gtab_kernel<<<257, 256, 0, stream>>>(hidden, Wib, Whb, bib, bhb, GiP, GhP);
    phase_kernel<1, 0><<<BB * NN, 512, 0, stream>>>(hidden, parent, child, GiP, GhP, h1, nullptr, nullptr);
    // Phase 2: fwd weights, x = parent, h = child; tgt gather fused
    gtab_kernel<<<257, 256, 0, stream>>>(h1, Wif, Whf, bif, bhf, GiP, GhP);
    phase_kernel<0, 1><<<BB * NN, 512, 0, stream>>>(h1, parent, child, GiP, GhP, nullptr, tgt, out);
}

// Round 9
// 66.889 us; speedup vs baseline: 5.2787x; 5.2787x over previous
//
#include <hip/hip_runtime.h>
#include <hip/hip_bf16.h>

#define ROWS 1025   // B*N + 1
#define DD   128    // D
#define C3   384    // 3*D
#define BB   8
#define NN   128

#define NL2E  (-1.4426950408889634f)   // -log2(e)

__device__ __forceinline__ unsigned short f2bf(float f) {
    unsigned int i = __float_as_uint(f);            // finite data only
    return (unsigned short)((i + 0x7FFFu + ((i >> 16) & 1u)) >> 16);
}

// Transpose + pre-scale the 4 weight matrices [384][128] -> [128][384]:
//   WT[k][cc] = W[cc][k] * (cc>=256 ? 2*NL2E : NL2E)
// 48 tiles (12 x 4 of 32x32) per matrix, 4 matrices = 192 blocks.
__global__ __launch_bounds__(256) void wprep_kernel(
    const float* __restrict__ Wib, const float* __restrict__ Whb,
    const float* __restrict__ Wif, const float* __restrict__ Whf,
    float* __restrict__ WT) {            // 4 contiguous [128][384] tables
    const int mat = blockIdx.x / 48, tile = blockIdx.x % 48;
    const int tr = tile / 4, tc = tile % 4;      // row-tile (cc), col-tile (k)
    const float* __restrict__ src = (mat == 0) ? Wib : (mat == 1) ? Whb
                                   : (mat == 2) ? Wif : Whf;
    float* __restrict__ dst = WT + (size_t)mat * DD * C3;
    __shared__ float tl[32][33];
    const int tx = threadIdx.x & 31, ty = threadIdx.x >> 5;   // 8 rows/pass
#pragma unroll
    for (int p = 0; p < 32; p += 8) {
        const int cc = tr * 32 + ty + p, k = tc * 32 + tx;
        const float sc = (cc >= 256) ? 2.0f * NL2E : NL2E;
        tl[ty + p][tx] = src[(size_t)cc * DD + k] * sc;
    }
    __syncthreads();
#pragma unroll
    for (int p = 0; p < 32; p += 8) {
        const int k = tc * 32 + ty + p, cc = tr * 32 + tx;
        dst[(size_t)k * C3 + cc] = tl[tx][ty + p];
    }
}

// Pre-scaled packed gate tables, bf16x4 per (row, d):
//   GiP[row][d] = {-L*ir, -L*iz, -2L*in, (unused)}
//   GhP[row][d] = {-L*hr, -L*hz, -2L*hn, h}
// Block = 4 hidden rows, 768 threads = one combined gate-column each
// (t<384: Gi col t; t>=384: Gh col t-384). Weight reads coalesced via WT
// ([k][cc] layout, pre-scaled). Hidden rows staged transposed: hsT[k][r],
// one broadcast ds_read_b128 per k yields all 4 rows.
__global__ __launch_bounds__(768) void gtab_kernel(
    const float* __restrict__ h,
    const float* __restrict__ WiT, const float* __restrict__ WhT,
    const float* __restrict__ bi, const float* __restrict__ bh,
    unsigned short* __restrict__ GiP, unsigned short* __restrict__ GhP) {
    __shared__ float hsT[DD][4];        // 2 KB
    const int t  = threadIdx.x;
    const int r0 = blockIdx.x * 4;
    if (t < 512) {
        const int r = t & 3, k = t >> 2;
        const int row = r0 + r;
        hsT[k][r] = (row < ROWS) ? h[(size_t)row * DD + k] : 0.0f;
    }
    __syncthreads();

    const bool isI  = t < C3;
    const int  cc   = isI ? t : t - C3;
    const int  gate = cc >> 7, d = cc & (DD - 1);
    const float* __restrict__ WT = isI ? WiT : WhT;
    const float scale = (gate == 2) ? 2.0f * NL2E : NL2E;
    const float bs = (isI ? bi : bh)[cc] * scale;   // weights pre-scaled in WT

    float a0 = 0.f, a1 = 0.f, a2 = 0.f, a3 = 0.f;
#pragma unroll 8
    for (int k = 0; k < DD; ++k) {
        const float  w  = WT[(size_t)k * C3 + cc];
        const float4 hv = *reinterpret_cast<const float4*>(&hsT[k][0]);
        a0 += w * hv.x; a1 += w * hv.y; a2 += w * hv.z; a3 += w * hv.w;
    }

    unsigned short* __restrict__ G = isI ? GiP : GhP;
    const float av[4] = {a0, a1, a2, a3};
#pragma unroll
    for (int r = 0; r < 4; ++r) {
        const int row = r0 + r;
        if (row < ROWS) G[(size_t)row * 512 + d * 4 + gate] = f2bf(av[r] + bs);
    }
    if (!isI && gate == 0) {            // h-value slot (GhP .w)
#pragma unroll
        for (int r = 0; r < 4; ++r) {
            const int row = r0 + r;
            if (row < ROWS) GhP[(size_t)row * 512 + d * 4 + 3] = f2bf(hsT[d][r]);
        }
    }
}

// One block per (b,j); 512 threads = (ic 0..3) x (d 0..127); quarter ic sums 32 i's.
// XC=1: x=child, h=parent (bwd). XC=0: x=parent, h=child (fwd).   [R6 verbatim]
template<int XC, int WRITE_OUT>
__global__ __launch_bounds__(512, 4) void phase_kernel(
    const float* __restrict__ hin,
    const int* __restrict__ parent, const int* __restrict__ child,
    const unsigned short* __restrict__ GiP, const unsigned short* __restrict__ GhP,
    float* __restrict__ hout,
    const int* __restrict__ tgt, float* __restrict__ out) {
    const int bj = blockIdx.x;          // 0..1023
    const int t  = threadIdx.x;
    const int b  = bj >> 7, j = bj & (NN - 1);
    const size_t base = (size_t)b * NN * NN + j;          // + i*NN

    __shared__ int   pcs[2 * NN];       // interleaved {p,c} pairs
    __shared__ float sacc[4][DD];
    if (t < NN)            pcs[2 * t]            = parent[base + (size_t)t * NN];
    else if (t < 2 * NN)   pcs[2 * (t - NN) + 1] = child [base + (size_t)(t - NN) * NN];
    __syncthreads();

    const int ic = t >> 7, d = t & (DD - 1);
    float acc = 0.0f;
#pragma unroll 4
    for (int k = 0; k < 32; ++k) {
        const int  i  = ic * 32 + k;
        const int2 pc = *reinterpret_cast<const int2*>(&pcs[2 * i]);
        const int  xi = XC ? pc.y : pc.x;
        const int  hi = XC ? pc.x : pc.y;
        const ushort4 vx = *reinterpret_cast<const ushort4*>(GiP + (size_t)xi * 512 + d * 4);
        const ushort4 vh = *reinterpret_cast<const ushort4*>(GhP + (size_t)hi * 512 + d * 4);
        const float irs = __uint_as_float(((unsigned int)vx.x) << 16);
        const float izs = __uint_as_float(((unsigned int)vx.y) << 16);
        const float ins = __uint_as_float(((unsigned int)vx.z) << 16);
        const float hrs = __uint_as_float(((unsigned int)vh.x) << 16);
        const float hzs = __uint_as_float(((unsigned int)vh.y) << 16);
        const float hns = __uint_as_float(((unsigned int)vh.z) << 16);
        const float hv  = __uint_as_float(((unsigned int)vh.w) << 16);
        const float r = __builtin_amdgcn_rcpf(1.0f + __builtin_amdgcn_exp2f(irs + hrs));
        const float z = __builtin_amdgcn_rcpf(1.0f + __builtin_amdgcn_exp2f(izs + hzs));
        const float q = __builtin_amdgcn_rcpf(1.0f + __builtin_amdgcn_exp2f(ins + r * hns));
        const float n = 2.0f * q - 1.0f;
        acc += n + z * (hv - n);
    }
    sacc[ic][d] = acc;
    __syncthreads();

    if (ic == 0) {
        const float v   = sacc[0][d] + sacc[1][d] + sacc[2][d] + sacc[3][d];
        const int   row = 1 + bj;
        const float res = hin[(size_t)row * DD + d] + v;
        if (WRITE_OUT) {
#pragma unroll
            for (int bb = 0; bb < BB; ++bb)
                if (tgt[bb] == row) out[bb * DD + d] = res;
        } else {
            hout[(size_t)row * DD + d] = res;
        }
    } else if (ic == 1 && bj == 0 && !WRITE_OUT) {
        hout[d] = hin[d];                 // row 0 unchanged (tgt >= 1 always)
    }
}

extern "C" void kernel_launch(void* const* d_in, const int* in_sizes, int n_in,
                              void* d_out, int out_size, void* d_ws, size_t ws_size,
                              hipStream_t stream) {
    const float* hidden = (const float*)d_in[0];
    const int*   parent = (const int*)d_in[1];
    const int*   child  = (const int*)d_in[2];
    const int*   tgt    = (const int*)d_in[3];
    const float* Wif    = (const float*)d_in[4];
    const float* Whf    = (const float*)d_in[5];
    const float* bif    = (const float*)d_in[6];
    const float* bhf    = (const float*)d_in[7];
    const float* Wib    = (const float*)d_in[8];
    const float* Whb    = (const float*)d_in[9];
    const float* bib    = (const float*)d_in[10];
    const float* bhb    = (const float*)d_in[11];

    char* ws = (char*)d_ws;
    float*          WT  = (float*)(ws);                    // 4 x 128x384 f32 = 786432 B
    unsigned short* GiP = (unsigned short*)(ws + 786432);  // 1025*512 bf16 = 1049600 B
    unsigned short* GhP = (unsigned short*)(ws + 1836032); // 1025*512 bf16
    float*          h1  = (float*)(ws + 2885632);          // 1025*128 f32
    float*          out = (float*)d_out;

    const float* WibT = WT;
    const float* WhbT = WT + DD * C3;
    const float* WifT = WT + 2 * DD * C3;
    const float* WhfT = WT + 3 * DD * C3;

    wprep_kernel<<<192, 256, 0, stream>>>(Wib, Whb, Wif, Whf, WT);
    // Phase 1: bwd weights, x = child, h = parent
    gtab_kernel<<<257, 768, 0, stream>>>(hidden, WibT, WhbT, bib, bhb, GiP, GhP);
    phase_kernel<1, 0><<<BB * NN, 512, 0, stream>>>(hidden, parent, child, GiP, GhP, h1, nullptr, nullptr);
    // Phase 2: fwd weights, x = parent, h = child; tgt gather fused
    gtab_kernel<<<257, 768, 0, stream>>>(h1, WifT, WhfT, bif, bhf, GiP, GhP);
    phase_kernel<0, 1><<<BB * NN, 512, 0, stream>>>(h1, parent, child, GiP, GhP, nullptr, tgt, out);
}